// Round 7
// baseline (252.063 us; speedup 1.0000x reference)
//
#include <hip/hip_runtime.h>
#include <hip/hip_bf16.h>

// ==== INSTRUMENTATION: REP on the two GEMMs only (idempotent). True cost = dur/REP. ====
#define REP_G256 3
#define REP_G2   4

// ---------- types ----------
typedef short bf16x8 __attribute__((ext_vector_type(8)));   // 8 bf16 = 4 VGPR
typedef float f32x4 __attribute__((ext_vector_type(4)));
typedef unsigned short ushort_t;

#define SQ 2048
#define DIM 1024
#define NH 16
#define HD 64

__device__ __forceinline__ ushort_t f2bf(float f) {
    uint32_t u = __builtin_bit_cast(uint32_t, f);
    u = (u + 0x7FFFu + ((u >> 16) & 1u)) >> 16;   // RNE
    return (ushort_t)u;
}

__device__ __forceinline__ void load_lds16(const void* g, void* l) {
    __builtin_amdgcn_global_load_lds(
        (const __attribute__((address_space(1))) unsigned int*)g,
        (__attribute__((address_space(3))) unsigned int*)l, 16, 0, 0);
}

// ---------- kernel 1: fp32 -> bf16 (vectorized) ----------
__global__ void cvt_x(const float* __restrict__ in, ushort_t* __restrict__ out, int n4) {
    int i = blockIdx.x * blockDim.x + threadIdx.x;
    int stride = gridDim.x * blockDim.x;
    for (; i < n4; i += stride) {
        float4 f = reinterpret_cast<const float4*>(in)[i];
        ushort4 o;
        o.x = f2bf(f.x); o.y = f2bf(f.y); o.z = f2bf(f.z); o.w = f2bf(f.w);
        reinterpret_cast<ushort4*>(out)[i] = o;
    }
}

// ---------- kernel 2: transpose + convert: in[R][C] fp32 -> out[C][R] bf16 ----------
__global__ void transpose_cvt(const float* __restrict__ in, ushort_t* __restrict__ out,
                              int R, int C) {
    __shared__ ushort_t tile[32][33];
    int c0 = blockIdx.x * 32, r0 = blockIdx.y * 32;
    int tx = threadIdx.x, ty = threadIdx.y;     // block (32,8)
#pragma unroll
    for (int i = 0; i < 32; i += 8)
        tile[ty + i][tx] = f2bf(in[(size_t)(r0 + ty + i) * C + c0 + tx]);
    __syncthreads();
#pragma unroll
    for (int i = 0; i < 32; i += 8)
        out[(size_t)(c0 + ty + i) * R + r0 + tx] = tile[tx][ty + i];
}

// ---------- kernel 2b: per-(b,h) V transpose ----------
__global__ void transpose_v(const ushort_t* __restrict__ qkv, ushort_t* __restrict__ vt) {
    __shared__ ushort_t tile[32][33];
    int s0 = blockIdx.x * 32, d0 = blockIdx.y * 32;
    int bh = blockIdx.z;                        // b*16+h
    int b = bh >> 4, h = bh & 15;
    const ushort_t* src = qkv + (size_t)(b * SQ) * 3072 + 2048 + h * 64;
    ushort_t* dst = vt + (size_t)bh * HD * SQ;
    int tx = threadIdx.x, ty = threadIdx.y;     // block (32,8)
#pragma unroll
    for (int i = 0; i < 32; i += 8)
        tile[ty + i][tx] = src[(size_t)(s0 + ty + i) * 3072 + d0 + tx];
    __syncthreads();
#pragma unroll
    for (int i = 0; i < 32; i += 8)
        dst[(size_t)(d0 + ty + i) * SQ + s0 + tx] = tile[tx][ty + i];
}

// =====================================================================
// 256x256 8-phase GEMM: C = A @ Bt^T + bias (bf16 out)
// =====================================================================

#define STAGE_HALF(Gptr, ldk, grow0, kcol, regionbase)                      \
  { _Pragma("unroll")                                                        \
    for (int j_ = 0; j_ < 2; ++j_) {                                         \
      int idx_ = j_ * 512 + tid;                                             \
      int row_ = idx_ >> 3;                                                  \
      int sc_ = (idx_ & 7) ^ (row_ & 7);                                     \
      load_lds16((Gptr) + (size_t)((grow0) + row_) * (ldk) + (kcol) + sc_ * 8, \
                 (regionbase) + idx_ * 16);                                  \
    } }

#define DS_A(BASE)                                                           \
  _Pragma("unroll") for (int kk_ = 0; kk_ < 2; ++kk_)                        \
  _Pragma("unroll") for (int m_ = 0; m_ < 4; ++m_)                           \
    a[kk_][m_] = *reinterpret_cast<const bf16x8*>((BASE) + offA[kk_][m_]);

#define DS_BL(BASE)                                                          \
  _Pragma("unroll") for (int kk_ = 0; kk_ < 2; ++kk_)                        \
  _Pragma("unroll") for (int n_ = 0; n_ < 2; ++n_)                           \
    bl[kk_][n_] = *reinterpret_cast<const bf16x8*>((BASE) + offB[kk_][n_]);

#define DS_BH(BASE)                                                          \
  _Pragma("unroll") for (int kk_ = 0; kk_ < 2; ++kk_)                        \
  _Pragma("unroll") for (int n_ = 0; n_ < 2; ++n_)                           \
    bh[kk_][n_] = *reinterpret_cast<const bf16x8*>((BASE) + offB[kk_][n_]);

#define BAR_LGKM                                                             \
  __builtin_amdgcn_s_barrier();                                              \
  asm volatile("s_waitcnt lgkmcnt(0)" ::: "memory");                         \
  __builtin_amdgcn_sched_barrier(0);

#define MFMA_CHUNK(MH, NHF, BB)                                              \
  __builtin_amdgcn_s_setprio(1);                                             \
  _Pragma("unroll") for (int kk_ = 0; kk_ < 2; ++kk_)                        \
  _Pragma("unroll") for (int m_ = 0; m_ < 4; ++m_)                           \
  _Pragma("unroll") for (int n_ = 0; n_ < 2; ++n_)                           \
    acc[(MH)*4 + m_][(NHF)*2 + n_] = __builtin_amdgcn_mfma_f32_16x16x32_bf16(\
        a[kk_][m_], BB[kk_][n_], acc[(MH)*4 + m_][(NHF)*2 + n_], 0, 0, 0);   \
  __builtin_amdgcn_s_setprio(0);

__global__ __launch_bounds__(512, 2)
void gemm256_bt(const ushort_t* __restrict__ A, const ushort_t* __restrict__ Bt,
                const float* __restrict__ bias, ushort_t* __restrict__ Cout,
                int M, int N, int K, int nbn) {
    __shared__ char sm[131072];
    const int tid = threadIdx.x;
    const int lane = tid & 63;
    const int w = tid >> 6;
    const int wm = w >> 2, wn = w & 3;
    const int r = lane & 15, hi = lane >> 4;

    const int cpx = gridDim.x >> 3;
    const int bid = blockIdx.x;
    const int x = (bid & 7) * cpx + (bid >> 3);
    const int bm = x / nbn, bn = x % nbn;
    const int m0 = bm * 256, n0 = bn * 256;

    const int NT = K >> 6;
    const int NI = NT >> 1;

    char* const A0l = sm;           char* const A0h = sm + 16384;
    char* const B0l = sm + 32768;   char* const B0h = sm + 49152;
    char* const A1l = sm + 65536;   char* const A1h = sm + 81920;
    char* const B1l = sm + 98304;   char* const B1h = sm + 114688;

    int offA[2][4], offB[2][2];
#pragma unroll
    for (int kk = 0; kk < 2; ++kk) {
#pragma unroll
        for (int m = 0; m < 4; ++m) {
            int rowL = wm * 64 + m * 16 + r;
            offA[kk][m] = rowL * 128 + (((kk * 4 + hi) ^ (rowL & 7)) * 16);
        }
#pragma unroll
        for (int n = 0; n < 2; ++n) {
            int rowL = wn * 32 + n * 16 + r;
            offB[kk][n] = rowL * 128 + (((kk * 4 + hi) ^ (rowL & 7)) * 16);
        }
    }

    for (int rep = 0; rep < REP_G256; ++rep) {
        // rep boundary: drain in-flight staging writes before restaging (race guard)
        asm volatile("s_waitcnt vmcnt(0)" ::: "memory");
        __builtin_amdgcn_s_barrier();

        f32x4 acc[8][4];
#pragma unroll
        for (int am = 0; am < 8; ++am)
#pragma unroll
            for (int an = 0; an < 4; ++an) acc[am][an] = (f32x4){0.f, 0.f, 0.f, 0.f};

        bf16x8 a[2][4], bl[2][2], bh[2][2];

        STAGE_HALF(A,  K, m0,       0, A0l);
        STAGE_HALF(Bt, K, n0,       0, B0l);
        STAGE_HALF(Bt, K, n0 + 128, 0, B0h);
        STAGE_HALF(A,  K, m0 + 128, 0, A0h);
        STAGE_HALF(A,  K, m0,      64, A1l);
        STAGE_HALF(Bt, K, n0,      64, B1l);
        asm volatile("s_waitcnt vmcnt(4)" ::: "memory");
        __builtin_amdgcn_s_barrier();

        for (int i = 0; i < NI; ++i) {
            const int k1 = (2 * i + 1) * 64;
            const int k2 = ((2 * i + 2) % NT) * 64;
            const int k3 = ((2 * i + 3) % NT) * 64;

            STAGE_HALF(A, K, m0 + 128, k1, A1h);
            DS_A(A0l); DS_BL(B0l);
            BAR_LGKM; MFMA_CHUNK(0, 0, bl);
            __builtin_amdgcn_s_barrier();

            STAGE_HALF(Bt, K, n0 + 128, k1, B1h);
            DS_BH(B0h);
            BAR_LGKM; MFMA_CHUNK(0, 1, bh);
            __builtin_amdgcn_s_barrier();

            STAGE_HALF(A, K, m0, k2, A0l);
            DS_A(A0h);
            BAR_LGKM; MFMA_CHUNK(1, 0, bl);
            __builtin_amdgcn_s_barrier();

            STAGE_HALF(Bt, K, n0, k2, B0l);
            BAR_LGKM; MFMA_CHUNK(1, 1, bh);
            asm volatile("s_waitcnt vmcnt(4)" ::: "memory");
            __builtin_amdgcn_s_barrier();

            STAGE_HALF(A, K, m0 + 128, k2, A0h);
            DS_A(A1l); DS_BL(B1l);
            BAR_LGKM; MFMA_CHUNK(0, 0, bl);
            __builtin_amdgcn_s_barrier();

            STAGE_HALF(Bt, K, n0 + 128, k2, B0h);
            DS_BH(B1h);
            BAR_LGKM; MFMA_CHUNK(0, 1, bh);
            __builtin_amdgcn_s_barrier();

            STAGE_HALF(A, K, m0, k3, A1l);
            DS_A(A1h);
            BAR_LGKM; MFMA_CHUNK(1, 0, bl);
            __builtin_amdgcn_s_barrier();

            STAGE_HALF(Bt, K, n0, k3, B1l);
            BAR_LGKM; MFMA_CHUNK(1, 1, bh);
            asm volatile("s_waitcnt vmcnt(4)" ::: "memory");
            __builtin_amdgcn_s_barrier();
        }

#pragma unroll
        for (int am = 0; am < 8; ++am) {
            int rowg = m0 + (am >> 2) * 128 + wm * 64 + (am & 3) * 16 + hi * 4;
#pragma unroll
            for (int an = 0; an < 4; ++an) {
                int colg = n0 + (an >> 1) * 128 + wn * 32 + (an & 1) * 16 + r;
                float bv = bias[colg];
#pragma unroll
                for (int j = 0; j < 4; ++j) {
                    float v = acc[am][an][j] + bv;
                    Cout[(size_t)(rowg + j) * N + colg] = f2bf(v);
                }
            }
        }
        __syncthreads();
    }
}

// ---------- GEMM2: 128x64 tile (512 blocks = 2/CU), f32 out + bias ----------
__global__ __launch_bounds__(256)
void gemm_bt2(const ushort_t* __restrict__ A, const ushort_t* __restrict__ Bt,
              const float* __restrict__ bias, float* __restrict__ Cout,
              int M, int N, int K) {
    __shared__ ushort_t sA[128 * 32];
    __shared__ ushort_t sB[64 * 32];
    const int tid = threadIdx.x;
    const int m0 = blockIdx.y * 128, n0 = blockIdx.x * 64;
    const int w = tid >> 6, lane = tid & 63;
    const int wr = w >> 1, wc = w & 1;          // 2x2 waves, each 64x32
    const int srow = tid >> 2, sch = tid & 3;
    const int r = lane & 15, hi = lane >> 4;

    for (int rep = 0; rep < REP_G2; ++rep) {
        f32x4 acc[4][2];
#pragma unroll
        for (int m = 0; m < 4; ++m)
#pragma unroll
            for (int n = 0; n < 2; ++n) acc[m][n] = (f32x4){0.f, 0.f, 0.f, 0.f};

        for (int k0 = 0; k0 < K; k0 += 32) {
            load_lds16(A + (size_t)(m0 + srow) * K + k0 + sch * 8,
                       (char*)sA + (size_t)srow * 64 + sch * 16);
            load_lds16(A + (size_t)(m0 + srow + 64) * K + k0 + sch * 8,
                       (char*)sA + (size_t)(srow + 64) * 64 + sch * 16);
            load_lds16(Bt + (size_t)(n0 + srow) * K + k0 + sch * 8,
                       (char*)sB + (size_t)srow * 64 + sch * 16);
            __syncthreads();

            bf16x8 af[4], bfr[2];
#pragma unroll
            for (int m = 0; m < 4; ++m)
                af[m] = *reinterpret_cast<const bf16x8*>(
                    (const char*)sA + (size_t)(wr * 64 + m * 16 + r) * 64 + hi * 16);
#pragma unroll
            for (int n = 0; n < 2; ++n)
                bfr[n] = *reinterpret_cast<const bf16x8*>(
                    (const char*)sB + (size_t)(wc * 32 + n * 16 + r) * 64 + hi * 16);
#pragma unroll
            for (int m = 0; m < 4; ++m)
#pragma unroll
                for (int n = 0; n < 2; ++n)
                    acc[m][n] = __builtin_amdgcn_mfma_f32_16x16x32_bf16(
                        af[m], bfr[n], acc[m][n], 0, 0, 0);
            __syncthreads();
        }

#pragma unroll
        for (int n = 0; n < 2; ++n) {
            int colg = n0 + wc * 32 + n * 16 + r;
            float bv = bias[colg];
#pragma unroll
            for (int m = 0; m < 4; ++m) {
                int rowg = m0 + wr * 64 + m * 16 + hi * 4;
#pragma unroll
                for (int j = 0; j < 4; ++j)
                    Cout[(size_t)(rowg + j) * N + colg] = acc[m][n][j] + bv;
            }
        }
        __syncthreads();
    }
}

// ---------- banded attention (R4 proven version: staged, band-skip, XCD swizzle) ----------
// LDS: sQ[64][64] swz @0 (8KB), sK[192][64] swz @8192 (24KB),
//      sVT[64][192] stride 384B swz @32768 (24KB), sP[64][200] aliases @0.
__global__ __launch_bounds__(256)
void attn_kernel(const ushort_t* __restrict__ qkv, const ushort_t* __restrict__ vt,
                 ushort_t* __restrict__ attn_out) {
    __shared__ uint4 smem4[57344 / 16];
    char* smem = (char*)smem4;

    const int bid0 = blockIdx.x;
    const int bid = (bid0 & 7) * 128 + (bid0 >> 3);   // XCD-chunked, 1024 % 8 == 0
    const int qb = bid & 31;
    const int h = (bid >> 5) & 15;
    const int b = bid >> 9;
    const int q0 = qb * 64;
    const int kstart = (q0 - 64 > 0) ? (q0 - 64) : 0;

    const int tid = threadIdx.x;
    const int lane = tid & 63;
    const int w = tid >> 6;
    const int r = lane & 15, hi = lane >> 4;

    // ---- stage Q [64][64] (swizzled rows) ----
#pragma unroll
    for (int i = 0; i < 2; ++i) {
        int task = i * 256 + tid;
        int row = task >> 3, ch = task & 7;
        uint4 v = *reinterpret_cast<const uint4*>(
            qkv + (size_t)(b * SQ + q0 + row) * 3072 + h * 64 + ch * 8);
        int byte = row * 128 + ch * 16; byte ^= (row & 7) << 4;
        *reinterpret_cast<uint4*>(smem + byte) = v;
    }
    // ---- stage K [192][64] (swizzled, zero-fill OOB) ----
#pragma unroll
    for (int i = 0; i < 6; ++i) {
        int task = i * 256 + tid;
        int row = task >> 3, ch = task & 7;
        int key = kstart + row;
        uint4 v = make_uint4(0u, 0u, 0u, 0u);
        if (key < SQ)
            v = *reinterpret_cast<const uint4*>(
                qkv + (size_t)(b * SQ + key) * 3072 + 1024 + h * 64 + ch * 8);
        int byte = row * 128 + ch * 16; byte ^= (row & 7) << 4;
        *reinterpret_cast<uint4*>(smem + 8192 + byte) = v;
    }
    // ---- stage V^T [64 d][192 k] from pre-transposed vt, vectorized ----
    {
        const ushort_t* vtb = vt + (size_t)(b * NH + h) * HD * SQ;
        int d = tid >> 2, cp = tid & 3;
#pragma unroll
        for (int i = 0; i < 6; ++i) {
            int c = cp + i * 4;                 // chunk 0..23 (16B each, 8 keys)
            uint4 v = make_uint4(0u, 0u, 0u, 0u);
            int k8 = kstart + c * 8;
            if (k8 < SQ)
                v = *reinterpret_cast<const uint4*>(vtb + (size_t)d * SQ + k8);
            int byte = d * 384 + (((c & 7) ^ (d & 7)) * 16) + ((c >> 3) * 128);
            *reinterpret_cast<uint4*>(smem + 32768 + byte) = v;
        }
    }
    __syncthreads();

    // ---- band tile range for this wave ----
    const int delta = q0 - kstart;              // 64 interior, 0 at qb==0
    const int base = w * 16 + delta;
    int tmin = (base - 64) >> 4; if (tmin < 0) tmin = 0;
    int tmax = (base + 79) >> 4;
    int tcap = (SQ - 1 - kstart) >> 4; if (tmax > tcap) tmax = tcap;
    if (tmax > 11) tmax = 11;
    const int ksmin = tmin >> 1, ksmax = tmax >> 1;

    // ---- scores: S[16q x 192k] per wave, band-skipped ----
    bf16x8 aq[2];
#pragma unroll
    for (int ks = 0; ks < 2; ++ks) {
        int row = w * 16 + r;
        int byte = row * 128 + ks * 64 + hi * 16; byte ^= (row & 7) << 4;
        aq[ks] = *reinterpret_cast<const bf16x8*>(smem + byte);
    }
    f32x4 acc[12];
#pragma unroll
    for (int t = 0; t < 12; ++t) acc[t] = (f32x4){0.f, 0.f, 0.f, 0.f};
#pragma unroll
    for (int t = 0; t < 12; ++t) {
        if (t < tmin || t > tmax) continue;     // wave-uniform skip
#pragma unroll
        for (int ks = 0; ks < 2; ++ks) {
            int row = t * 16 + r;
            int byte = row * 128 + ks * 64 + hi * 16; byte ^= (row & 7) << 4;
            bf16x8 bk = *reinterpret_cast<const bf16x8*>(smem + 8192 + byte);
            acc[t] = __builtin_amdgcn_mfma_f32_16x16x32_bf16(aq[ks], bk, acc[t], 0, 0, 0);
        }
    }

    // ---- mask + scale + softmax ----
    float mrow[4], lrow[4];
#pragma unroll
    for (int t = 0; t < 12; ++t) {
        if (t < tmin || t > tmax) continue;
        int key = kstart + t * 16 + r;
#pragma unroll
        for (int j = 0; j < 4; ++j) {
            int qrow = q0 + w * 16 + hi * 4 + j;
            int dd = key - qrow; if (dd < 0) dd = -dd;
            bool valid = (key < SQ) && (dd <= 64);
            acc[t][j] = valid ? acc[t][j] * 0.125f : -1e30f;
        }
    }
#pragma unroll
    for (int j = 0; j < 4; ++j) {
        float m = -1e30f;
#pragma unroll
        for (int t = 0; t < 12; ++t) {
            if (t < tmin || t > tmax) continue;
            m = fmaxf(m, acc[t][j]);
        }
        m = fmaxf(m, __shfl_xor(m, 1));
        m = fmaxf(m, __shfl_xor(m, 2));
        m = fmaxf(m, __shfl_xor(m, 4));
        m = fmaxf(m, __shfl_xor(m, 8));
        mrow[j] = m;
    }
#pragma unroll
    for (int j = 0; j < 4; ++j) {
        float s = 0.f;
#pragma unroll
        for (int t = 0; t < 12; ++t) {
            if (t < tmin || t > tmax) continue;
            float p = __expf(acc[t][j] - mrow[j]);
            acc[t][j] = p;
            s += p;
        }
        s += __shfl_xor(s, 1);
        s += __shfl_xor(s, 2);
        s += __shfl_xor(s, 4);
        s += __shfl_xor(s, 8);
        lrow[j] = s;
    }

    __syncthreads();   // done reading sQ/sK before P overwrites them

    // ---- write P to LDS [64][200] (stride 400B), zeros outside band ----
#pragma unroll
    for (int t = 0; t < 12; ++t) {
        int col = t * 16 + r;
        bool inb = (t >= tmin) && (t <= tmax);
#pragma unroll
        for (int j = 0; j < 4; ++j) {
            int rowL = w * 16 + hi * 4 + j;
            ushort_t pv = inb ? f2bf(acc[t][j]) : (ushort_t)0;
            *reinterpret_cast<ushort_t*>(smem + rowL * 400 + col * 2) = pv;
        }
    }
    __syncthreads();

    // ---- PV: O[16q x 64d]; band-skipped k-chunks ----
    f32x4 oacc[4];
#pragma unroll
    for (int dt = 0; dt < 4; ++dt) oacc[dt] = (f32x4){0.f, 0.f, 0.f, 0.f};
#pragma unroll
    for (int ks = 0; ks < 6; ++ks) {
        if (ks < ksmin || ks > ksmax) continue;
        int k0 = ks * 32 + hi * 8;
        bf16x8 ap = *reinterpret_cast<const bf16x8*>(smem + (w * 16 + r) * 400 + k0 * 2);
        int cch = ks * 4 + hi;                  // 16B chunk index 0..23
#pragma unroll
        for (int dt = 0; dt < 4; ++dt) {
            int d = dt * 16 + r;
            int byte = d * 384 + (((cch & 7) ^ (d & 7)) * 16) + ((cch >> 3) * 128);
            bf16x8 bv = *reinterpret_cast<const bf16x8*>(smem + 32768 + byte);
            oacc[dt] = __builtin_amdgcn_mfma_f32_16x16x32_bf16(ap, bv, oacc[dt], 0, 0, 0);
        }
    }

    // ---- normalize + store ----
    float inv[4];
#pragma unroll
    for (int j = 0; j < 4; ++j) inv[j] = 1.0f / lrow[j];
#pragma unroll
    for (int dt = 0; dt < 4; ++dt) {
        int d = dt * 16 + r;
#pragma unroll
        for (int j = 0; j < 4; ++j) {
            int q = q0 + w * 16 + hi * 4 + j;
            attn_out[(size_t)(b * SQ + q) * 1024 + h * 64 + d] = f2bf(oacc[dt][j] * inv[j]);
        }
    }
}

// ---------- launch ----------
extern "C" void kernel_launch(void* const* d_in, const int* in_sizes, int n_in,
                              void* d_out, int out_size, void* d_ws, size_t ws_size,
                              hipStream_t stream) {
    const float* x     = (const float*)d_in[0];
    const float* w_qkv = (const float*)d_in[1];
    const float* b_qkv = (const float*)d_in[2];
    const float* w_out = (const float*)d_in[3];
    const float* b_out = (const float*)d_in[4];
    float* out = (float*)d_out;

    char* ws = (char*)d_ws;
    ushort_t* xb    = (ushort_t*)(ws);                       // 8 MB  [4096][1024]
    ushort_t* wqkvT = (ushort_t*)(ws + 8388608);             // 6 MB  [3072][1024]
    ushort_t* woutT = (ushort_t*)(ws + 14680064);            // 2 MB  [1024][1024]
    ushort_t* qkv   = (ushort_t*)(ws + 16777216);            // 24 MB [4096][3072]
    ushort_t* aout  = (ushort_t*)(ws + 41943040);            // 8 MB  [4096][1024]
    ushort_t* vtbuf = (ushort_t*)(ws + 50331648);            // 8 MB  [32][64][2048]

    cvt_x<<<1024, 256, 0, stream>>>(x, xb, 4096 * 1024 / 4);
    transpose_cvt<<<dim3(96, 32), dim3(32, 8), 0, stream>>>(w_qkv, wqkvT, 1024, 3072);
    transpose_cvt<<<dim3(32, 32), dim3(32, 8), 0, stream>>>(w_out, woutT, 1024, 1024);

    gemm256_bt<<<192, 512, 0, stream>>>(xb, wqkvT, b_qkv, qkv, 4096, 3072, 1024, 12);
    transpose_v<<<dim3(64, 2, 32), dim3(32, 8), 0, stream>>>(qkv, vtbuf);
    attn_kernel<<<1024, 256, 0, stream>>>(qkv, vtbuf, aout);
    gemm_bt2<<<dim3(16, 32), 256, 0, stream>>>(aout, woutT, b_out, out, 4096, 1024, 1024);
}

// Round 8
// 94.736 us; speedup vs baseline: 2.6607x; 2.6607x over previous
//
#include <hip/hip_runtime.h>
#include <hip/hip_bf16.h>

// ---------- types ----------
typedef short bf16x8 __attribute__((ext_vector_type(8)));   // 8 bf16 = 4 VGPR
typedef float f32x4 __attribute__((ext_vector_type(4)));
typedef unsigned short ushort_t;

#define SQ 2048
#define DIM 1024
#define NH 16
#define HD 64

__device__ __forceinline__ ushort_t f2bf(float f) {
    uint32_t u = __builtin_bit_cast(uint32_t, f);
    u = (u + 0x7FFFu + ((u >> 16) & 1u)) >> 16;   // RNE
    return (ushort_t)u;
}

__device__ __forceinline__ void load_lds16(const void* g, void* l) {
    __builtin_amdgcn_global_load_lds(
        (const __attribute__((address_space(1))) unsigned int*)g,
        (__attribute__((address_space(3))) unsigned int*)l, 16, 0, 0);
}

// ---------- kernel 1: fp32 -> bf16 (vectorized) ----------
__global__ void cvt_x(const float* __restrict__ in, ushort_t* __restrict__ out, int n4) {
    int i = blockIdx.x * blockDim.x + threadIdx.x;
    int stride = gridDim.x * blockDim.x;
    for (; i < n4; i += stride) {
        float4 f = reinterpret_cast<const float4*>(in)[i];
        ushort4 o;
        o.x = f2bf(f.x); o.y = f2bf(f.y); o.z = f2bf(f.z); o.w = f2bf(f.w);
        reinterpret_cast<ushort4*>(out)[i] = o;
    }
}

// ---------- kernel 2: transpose + convert: in[R][C] fp32 -> out[C][R] bf16 ----------
__global__ void transpose_cvt(const float* __restrict__ in, ushort_t* __restrict__ out,
                              int R, int C) {
    __shared__ ushort_t tile[32][33];
    int c0 = blockIdx.x * 32, r0 = blockIdx.y * 32;
    int tx = threadIdx.x, ty = threadIdx.y;     // block (32,8)
#pragma unroll
    for (int i = 0; i < 32; i += 8)
        tile[ty + i][tx] = f2bf(in[(size_t)(r0 + ty + i) * C + c0 + tx]);
    __syncthreads();
#pragma unroll
    for (int i = 0; i < 32; i += 8)
        out[(size_t)(c0 + ty + i) * R + r0 + tx] = tile[tx][ty + i];
}

// ---------- kernel 2b: per-(b,h) V transpose ----------
__global__ void transpose_v(const ushort_t* __restrict__ qkv, ushort_t* __restrict__ vt) {
    __shared__ ushort_t tile[32][33];
    int s0 = blockIdx.x * 32, d0 = blockIdx.y * 32;
    int bh = blockIdx.z;                        // b*16+h
    int b = bh >> 4, h = bh & 15;
    const ushort_t* src = qkv + (size_t)(b * SQ) * 3072 + 2048 + h * 64;
    ushort_t* dst = vt + (size_t)bh * HD * SQ;
    int tx = threadIdx.x, ty = threadIdx.y;     // block (32,8)
#pragma unroll
    for (int i = 0; i < 32; i += 8)
        tile[ty + i][tx] = src[(size_t)(s0 + ty + i) * 3072 + d0 + tx];
    __syncthreads();
#pragma unroll
    for (int i = 0; i < 32; i += 8)
        dst[(size_t)(d0 + ty + i) * SQ + s0 + tx] = tile[tx][ty + i];
}

// =====================================================================
// 256x256 8-phase GEMM (unchanged): C = A @ Bt^T + bias (bf16 out)
// =====================================================================

#define STAGE_HALF(Gptr, ldk, grow0, kcol, regionbase)                      \
  { _Pragma("unroll")                                                        \
    for (int j_ = 0; j_ < 2; ++j_) {                                         \
      int idx_ = j_ * 512 + tid;                                             \
      int row_ = idx_ >> 3;                                                  \
      int sc_ = (idx_ & 7) ^ (row_ & 7);                                     \
      load_lds16((Gptr) + (size_t)((grow0) + row_) * (ldk) + (kcol) + sc_ * 8, \
                 (regionbase) + idx_ * 16);                                  \
    } }

#define DS_A(BASE)                                                           \
  _Pragma("unroll") for (int kk_ = 0; kk_ < 2; ++kk_)                        \
  _Pragma("unroll") for (int m_ = 0; m_ < 4; ++m_)                           \
    a[kk_][m_] = *reinterpret_cast<const bf16x8*>((BASE) + offA[kk_][m_]);

#define DS_BL(BASE)                                                          \
  _Pragma("unroll") for (int kk_ = 0; kk_ < 2; ++kk_)                        \
  _Pragma("unroll") for (int n_ = 0; n_ < 2; ++n_)                           \
    bl[kk_][n_] = *reinterpret_cast<const bf16x8*>((BASE) + offB[kk_][n_]);

#define DS_BH(BASE)                                                          \
  _Pragma("unroll") for (int kk_ = 0; kk_ < 2; ++kk_)                        \
  _Pragma("unroll") for (int n_ = 0; n_ < 2; ++n_)                           \
    bh[kk_][n_] = *reinterpret_cast<const bf16x8*>((BASE) + offB[kk_][n_]);

#define BAR_LGKM                                                             \
  __builtin_amdgcn_s_barrier();                                              \
  asm volatile("s_waitcnt lgkmcnt(0)" ::: "memory");                         \
  __builtin_amdgcn_sched_barrier(0);

#define MFMA_CHUNK(MH, NHF, BB)                                              \
  __builtin_amdgcn_s_setprio(1);                                             \
  _Pragma("unroll") for (int kk_ = 0; kk_ < 2; ++kk_)                        \
  _Pragma("unroll") for (int m_ = 0; m_ < 4; ++m_)                           \
  _Pragma("unroll") for (int n_ = 0; n_ < 2; ++n_)                           \
    acc[(MH)*4 + m_][(NHF)*2 + n_] = __builtin_amdgcn_mfma_f32_16x16x32_bf16(\
        a[kk_][m_], BB[kk_][n_], acc[(MH)*4 + m_][(NHF)*2 + n_], 0, 0, 0);   \
  __builtin_amdgcn_s_setprio(0);

__global__ __launch_bounds__(512, 2)
void gemm256_bt(const ushort_t* __restrict__ A, const ushort_t* __restrict__ Bt,
                const float* __restrict__ bias, ushort_t* __restrict__ Cout,
                int M, int N, int K, int nbn) {
    __shared__ char sm[131072];
    const int tid = threadIdx.x;
    const int lane = tid & 63;
    const int w = tid >> 6;
    const int wm = w >> 2, wn = w & 3;
    const int r = lane & 15, hi = lane >> 4;

    const int cpx = gridDim.x >> 3;
    const int bid = blockIdx.x;
    const int x = (bid & 7) * cpx + (bid >> 3);
    const int bm = x / nbn, bn = x % nbn;
    const int m0 = bm * 256, n0 = bn * 256;

    const int NT = K >> 6;
    const int NI = NT >> 1;

    char* const A0l = sm;           char* const A0h = sm + 16384;
    char* const B0l = sm + 32768;   char* const B0h = sm + 49152;
    char* const A1l = sm + 65536;   char* const A1h = sm + 81920;
    char* const B1l = sm + 98304;   char* const B1h = sm + 114688;

    int offA[2][4], offB[2][2];
#pragma unroll
    for (int kk = 0; kk < 2; ++kk) {
#pragma unroll
        for (int m = 0; m < 4; ++m) {
            int rowL = wm * 64 + m * 16 + r;
            offA[kk][m] = rowL * 128 + (((kk * 4 + hi) ^ (rowL & 7)) * 16);
        }
#pragma unroll
        for (int n = 0; n < 2; ++n) {
            int rowL = wn * 32 + n * 16 + r;
            offB[kk][n] = rowL * 128 + (((kk * 4 + hi) ^ (rowL & 7)) * 16);
        }
    }

    f32x4 acc[8][4];
#pragma unroll
    for (int am = 0; am < 8; ++am)
#pragma unroll
        for (int an = 0; an < 4; ++an) acc[am][an] = (f32x4){0.f, 0.f, 0.f, 0.f};

    bf16x8 a[2][4], bl[2][2], bh[2][2];

    STAGE_HALF(A,  K, m0,       0, A0l);
    STAGE_HALF(Bt, K, n0,       0, B0l);
    STAGE_HALF(Bt, K, n0 + 128, 0, B0h);
    STAGE_HALF(A,  K, m0 + 128, 0, A0h);
    STAGE_HALF(A,  K, m0,      64, A1l);
    STAGE_HALF(Bt, K, n0,      64, B1l);
    asm volatile("s_waitcnt vmcnt(4)" ::: "memory");
    __builtin_amdgcn_s_barrier();

    for (int i = 0; i < NI; ++i) {
        const int k1 = (2 * i + 1) * 64;
        const int k2 = ((2 * i + 2) % NT) * 64;
        const int k3 = ((2 * i + 3) % NT) * 64;

        STAGE_HALF(A, K, m0 + 128, k1, A1h);
        DS_A(A0l); DS_BL(B0l);
        BAR_LGKM; MFMA_CHUNK(0, 0, bl);
        __builtin_amdgcn_s_barrier();

        STAGE_HALF(Bt, K, n0 + 128, k1, B1h);
        DS_BH(B0h);
        BAR_LGKM; MFMA_CHUNK(0, 1, bh);
        __builtin_amdgcn_s_barrier();

        STAGE_HALF(A, K, m0, k2, A0l);
        DS_A(A0h);
        BAR_LGKM; MFMA_CHUNK(1, 0, bl);
        __builtin_amdgcn_s_barrier();

        STAGE_HALF(Bt, K, n0, k2, B0l);
        BAR_LGKM; MFMA_CHUNK(1, 1, bh);
        asm volatile("s_waitcnt vmcnt(4)" ::: "memory");
        __builtin_amdgcn_s_barrier();

        STAGE_HALF(A, K, m0 + 128, k2, A0h);
        DS_A(A1l); DS_BL(B1l);
        BAR_LGKM; MFMA_CHUNK(0, 0, bl);
        __builtin_amdgcn_s_barrier();

        STAGE_HALF(Bt, K, n0 + 128, k2, B0h);
        DS_BH(B1h);
        BAR_LGKM; MFMA_CHUNK(0, 1, bh);
        __builtin_amdgcn_s_barrier();

        STAGE_HALF(A, K, m0, k3, A1l);
        DS_A(A1h);
        BAR_LGKM; MFMA_CHUNK(1, 0, bl);
        __builtin_amdgcn_s_barrier();

        STAGE_HALF(Bt, K, n0, k3, B1l);
        BAR_LGKM; MFMA_CHUNK(1, 1, bh);
        asm volatile("s_waitcnt vmcnt(4)" ::: "memory");
        __builtin_amdgcn_s_barrier();
    }

#pragma unroll
    for (int am = 0; am < 8; ++am) {
        int rowg = m0 + (am >> 2) * 128 + wm * 64 + (am & 3) * 16 + hi * 4;
#pragma unroll
        for (int an = 0; an < 4; ++an) {
            int colg = n0 + (an >> 1) * 128 + wn * 32 + (an & 1) * 16 + r;
            float bv = bias[colg];
#pragma unroll
            for (int j = 0; j < 4; ++j) {
                float v = acc[am][an][j] + bv;
                Cout[(size_t)(rowg + j) * N + colg] = f2bf(v);
            }
        }
    }
}

// ---------- GEMM2: 128x64 tile, BK=64, both-sides swizzle (conflict-free) ----------
__global__ __launch_bounds__(256)
void gemm_bt2(const ushort_t* __restrict__ A, const ushort_t* __restrict__ Bt,
              const float* __restrict__ bias, float* __restrict__ Cout,
              int M, int N, int K) {
    __shared__ char sA[16384];    // 128 rows x 128B, chunk-XOR swizzled
    __shared__ char sB[8192];     // 64 rows x 128B, chunk-XOR swizzled
    const int tid = threadIdx.x;
    const int m0 = blockIdx.y * 128, n0 = blockIdx.x * 64;
    const int w = tid >> 6, lane = tid & 63;
    const int wr = w >> 1, wc = w & 1;          // 2x2 waves, each 64x32
    const int r = lane & 15, hi = lane >> 4;

    f32x4 acc[4][2];
#pragma unroll
    for (int m = 0; m < 4; ++m)
#pragma unroll
        for (int n = 0; n < 2; ++n) acc[m][n] = (f32x4){0.f, 0.f, 0.f, 0.f};

    for (int k0 = 0; k0 < K; k0 += 64) {
        // stage A 128x64 (4 chunks/thread), pre-swizzled global source
#pragma unroll
        for (int i = 0; i < 4; ++i) {
            int task = i * 256 + tid;
            int row = task >> 3;
            int sc = (task & 7) ^ (row & 7);
            load_lds16(A + (size_t)(m0 + row) * K + k0 + sc * 8, sA + task * 16);
        }
        // stage B 64x64 (2 chunks/thread)
#pragma unroll
        for (int i = 0; i < 2; ++i) {
            int task = i * 256 + tid;
            int row = task >> 3;
            int sc = (task & 7) ^ (row & 7);
            load_lds16(Bt + (size_t)(n0 + row) * K + k0 + sc * 8, sB + task * 16);
        }
        __syncthreads();

#pragma unroll
        for (int ks = 0; ks < 2; ++ks) {
            bf16x8 af[4], bfr[2];
#pragma unroll
            for (int m = 0; m < 4; ++m) {
                int row = wr * 64 + m * 16 + r;
                af[m] = *reinterpret_cast<const bf16x8*>(
                    sA + row * 128 + (((ks * 4 + hi) ^ (row & 7)) * 16));
            }
#pragma unroll
            for (int n = 0; n < 2; ++n) {
                int row = wc * 32 + n * 16 + r;
                bfr[n] = *reinterpret_cast<const bf16x8*>(
                    sB + row * 128 + (((ks * 4 + hi) ^ (row & 7)) * 16));
            }
#pragma unroll
            for (int m = 0; m < 4; ++m)
#pragma unroll
                for (int n = 0; n < 2; ++n)
                    acc[m][n] = __builtin_amdgcn_mfma_f32_16x16x32_bf16(
                        af[m], bfr[n], acc[m][n], 0, 0, 0);
        }
        __syncthreads();
    }

#pragma unroll
    for (int n = 0; n < 2; ++n) {
        int colg = n0 + wc * 32 + n * 16 + r;
        float bv = bias[colg];
#pragma unroll
        for (int m = 0; m < 4; ++m) {
            int rowg = m0 + wr * 64 + m * 16 + hi * 4;
#pragma unroll
            for (int j = 0; j < 4; ++j)
                Cout[(size_t)(rowg + j) * N + colg] = acc[m][n][j] + bv;
        }
    }
}

// ---------- banded attention: single-barrier version ----------
// Q -> registers directly (per-wave A-frag). LDS: K[192][64] swz @0 (24KB),
// VT[64][192] swz @24576 (24KB), P private-per-wave [64][200] @49152 (25.6KB).
// Each wave writes/reads ONLY its own 16 P rows -> no barrier around P.
__global__ __launch_bounds__(256)
void attn_kernel(const ushort_t* __restrict__ qkv, const ushort_t* __restrict__ vt,
                 ushort_t* __restrict__ attn_out) {
    __shared__ char smem[74752];

    const int bid0 = blockIdx.x;
    const int bid = (bid0 & 7) * 128 + (bid0 >> 3);   // XCD-chunked, 1024 % 8 == 0
    const int qb = bid & 31;
    const int h = (bid >> 5) & 15;
    const int b = bid >> 9;
    const int q0 = qb * 64;
    const int kstart = (q0 - 64 > 0) ? (q0 - 64) : 0;

    const int tid = threadIdx.x;
    const int lane = tid & 63;
    const int w = tid >> 6;
    const int r = lane & 15, hi = lane >> 4;

    // ---- stage K [192][64] @0 (swizzled, zero-fill OOB) ----
#pragma unroll
    for (int i = 0; i < 6; ++i) {
        int task = i * 256 + tid;
        int row = task >> 3, ch = task & 7;
        int key = kstart + row;
        uint4 v = make_uint4(0u, 0u, 0u, 0u);
        if (key < SQ)
            v = *reinterpret_cast<const uint4*>(
                qkv + (size_t)(b * SQ + key) * 3072 + 1024 + h * 64 + ch * 8);
        int byte = row * 128 + ch * 16; byte ^= (row & 7) << 4;
        *reinterpret_cast<uint4*>(smem + byte) = v;
    }
    // ---- stage V^T [64 d][192 k] @24576 from pre-transposed vt ----
    {
        const ushort_t* vtb = vt + (size_t)(b * NH + h) * HD * SQ;
        int d = tid >> 2, cp = tid & 3;
#pragma unroll
        for (int i = 0; i < 6; ++i) {
            int c = cp + i * 4;                 // chunk 0..23 (16B each, 8 keys)
            uint4 v = make_uint4(0u, 0u, 0u, 0u);
            int k8 = kstart + c * 8;
            if (k8 < SQ)
                v = *reinterpret_cast<const uint4*>(vtb + (size_t)d * SQ + k8);
            int byte = d * 384 + (((c & 7) ^ (d & 7)) * 16) + ((c >> 3) * 128);
            *reinterpret_cast<uint4*>(smem + 24576 + byte) = v;
        }
    }

    // ---- Q directly into A-fragments (own wave's 16 rows; q0+w*16+r < 2048 always) ----
    const ushort_t* qrow = qkv + (size_t)(b * SQ + q0 + w * 16 + r) * 3072 + h * 64;
    bf16x8 aq0 = *reinterpret_cast<const bf16x8*>(qrow + hi * 8);
    bf16x8 aq1 = *reinterpret_cast<const bf16x8*>(qrow + 32 + hi * 8);

    __syncthreads();   // the ONLY block-wide barrier

    // ---- band tile range for this wave ----
    const int delta = q0 - kstart;              // 64 interior, 0 at qb==0
    const int base = w * 16 + delta;
    int tmin = (base - 64) >> 4; if (tmin < 0) tmin = 0;
    int tmax = (base + 79) >> 4;
    int tcap = (SQ - 1 - kstart) >> 4; if (tmax > tcap) tmax = tcap;
    if (tmax > 11) tmax = 11;
    const int ksmin = tmin >> 1, ksmax = tmax >> 1;

    // ---- scores: S[16q x 192k] per wave, band-skipped ----
    f32x4 acc[12];
#pragma unroll
    for (int t = 0; t < 12; ++t) acc[t] = (f32x4){0.f, 0.f, 0.f, 0.f};
#pragma unroll
    for (int t = 0; t < 12; ++t) {
        if (t < tmin || t > tmax) continue;     // wave-uniform skip
#pragma unroll
        for (int ks = 0; ks < 2; ++ks) {
            int row = t * 16 + r;
            int byte = row * 128 + ks * 64 + hi * 16; byte ^= (row & 7) << 4;
            bf16x8 bk = *reinterpret_cast<const bf16x8*>(smem + byte);
            acc[t] = __builtin_amdgcn_mfma_f32_16x16x32_bf16(
                ks == 0 ? aq0 : aq1, bk, acc[t], 0, 0, 0);
        }
    }

    // ---- mask + scale + softmax ----
    float mrow[4], lrow[4];
#pragma unroll
    for (int t = 0; t < 12; ++t) {
        if (t < tmin || t > tmax) continue;
        int key = kstart + t * 16 + r;
#pragma unroll
        for (int j = 0; j < 4; ++j) {
            int qrow_g = q0 + w * 16 + hi * 4 + j;
            int dd = key - qrow_g; if (dd < 0) dd = -dd;
            bool valid = (key < SQ) && (dd <= 64);
            acc[t][j] = valid ? acc[t][j] * 0.125f : -1e30f;
        }
    }
#pragma unroll
    for (int j = 0; j < 4; ++j) {
        float m = -1e30f;
#pragma unroll
        for (int t = 0; t < 12; ++t) {
            if (t < tmin || t > tmax) continue;
            m = fmaxf(m, acc[t][j]);
        }
        m = fmaxf(m, __shfl_xor(m, 1));
        m = fmaxf(m, __shfl_xor(m, 2));
        m = fmaxf(m, __shfl_xor(m, 4));
        m = fmaxf(m, __shfl_xor(m, 8));
        mrow[j] = m;
    }
#pragma unroll
    for (int j = 0; j < 4; ++j) {
        float s = 0.f;
#pragma unroll
        for (int t = 0; t < 12; ++t) {
            if (t < tmin || t > tmax) continue;
            float p = __expf(acc[t][j] - mrow[j]);
            acc[t][j] = p;
            s += p;
        }
        s += __shfl_xor(s, 1);
        s += __shfl_xor(s, 2);
        s += __shfl_xor(s, 4);
        s += __shfl_xor(s, 8);
        lrow[j] = s;
    }

    // ---- write P to own wave's private LDS rows @49152 (stride 400B) ----
#pragma unroll
    for (int t = 0; t < 12; ++t) {
        int col = t * 16 + r;
        bool inb = (t >= tmin) && (t <= tmax);
#pragma unroll
        for (int j = 0; j < 4; ++j) {
            int rowL = w * 16 + hi * 4 + j;
            ushort_t pv = inb ? f2bf(acc[t][j]) : (ushort_t)0;
            *reinterpret_cast<ushort_t*>(smem + 49152 + rowL * 400 + col * 2) = pv;
        }
    }
    // same-wave write->read dependency: compiler inserts lgkmcnt; no barrier.

    // ---- PV: O[16q x 64d]; band-skipped k-chunks ----
    f32x4 oacc[4];
#pragma unroll
    for (int dt = 0; dt < 4; ++dt) oacc[dt] = (f32x4){0.f, 0.f, 0.f, 0.f};
#pragma unroll
    for (int ks = 0; ks < 6; ++ks) {
        if (ks < ksmin || ks > ksmax) continue;
        int k0 = ks * 32 + hi * 8;
        bf16x8 ap = *reinterpret_cast<const bf16x8*>(
            smem + 49152 + (w * 16 + r) * 400 + k0 * 2);
        int cch = ks * 4 + hi;                  // 16B chunk index 0..23
#pragma unroll
        for (int dt = 0; dt < 4; ++dt) {
            int d = dt * 16 + r;
            int byte = d * 384 + (((cch & 7) ^ (d & 7)) * 16) + ((cch >> 3) * 128);
            bf16x8 bv = *reinterpret_cast<const bf16x8*>(smem + 24576 + byte);
            oacc[dt] = __builtin_amdgcn_mfma_f32_16x16x32_bf16(ap, bv, oacc[dt], 0, 0, 0);
        }
    }

    // ---- normalize + store ----
    float inv[4];
#pragma unroll
    for (int j = 0; j < 4; ++j) inv[j] = 1.0f / lrow[j];
#pragma unroll
    for (int dt = 0; dt < 4; ++dt) {
        int d = dt * 16 + r;
#pragma unroll
        for (int j = 0; j < 4; ++j) {
            int q = q0 + w * 16 + hi * 4 + j;
            attn_out[(size_t)(b * SQ + q) * 1024 + h * 64 + d] = f2bf(oacc[dt][j] * inv[j]);
        }
    }
}

// ---------- launch ----------
extern "C" void kernel_launch(void* const* d_in, const int* in_sizes, int n_in,
                              void* d_out, int out_size, void* d_ws, size_t ws_size,
                              hipStream_t stream) {
    const float* x     = (const float*)d_in[0];
    const float* w_qkv = (const float*)d_in[1];
    const float* b_qkv = (const float*)d_in[2];
    const float* w_out = (const float*)d_in[3];
    const float* b_out = (const float*)d_in[4];
    float* out = (float*)d_out;

    char* ws = (char*)d_ws;
    ushort_t* xb    = (ushort_t*)(ws);                       // 8 MB  [4096][1024]
    ushort_t* wqkvT = (ushort_t*)(ws + 8388608);             // 6 MB  [3072][1024]
    ushort_t* woutT = (ushort_t*)(ws + 14680064);            // 2 MB  [1024][1024]
    ushort_t* qkv   = (ushort_t*)(ws + 16777216);            // 24 MB [4096][3072]
    ushort_t* aout  = (ushort_t*)(ws + 41943040);            // 8 MB  [4096][1024]
    ushort_t* vtbuf = (ushort_t*)(ws + 50331648);            // 8 MB  [32][64][2048]

    cvt_x<<<1024, 256, 0, stream>>>(x, xb, 4096 * 1024 / 4);
    transpose_cvt<<<dim3(96, 32), dim3(32, 8), 0, stream>>>(w_qkv, wqkvT, 1024, 3072);
    transpose_cvt<<<dim3(32, 32), dim3(32, 8), 0, stream>>>(w_out, woutT, 1024, 1024);

    gemm256_bt<<<192, 512, 0, stream>>>(xb, wqkvT, b_qkv, qkv, 4096, 3072, 1024, 12);
    transpose_v<<<dim3(64, 2, 32), dim3(32, 8), 0, stream>>>(qkv, vtbuf);
    attn_kernel<<<1024, 256, 0, stream>>>(qkv, vtbuf, aout);
    gemm_bt2<<<dim3(16, 32), 256, 0, stream>>>(aout, woutT, b_out, out, 4096, 1024, 1024);
}